// Round 15
// baseline (726.265 us; speedup 1.0000x reference)
//
#include <hip/hip_runtime.h>

#define B 4
#define CIN 256
#define T 8192
#define NL 24
#define SH 0.70710678118654752f
#define SKIP_SCALE 0.20412414523193150f  // (1/24)^0.5

typedef unsigned short u16;
typedef __attribute__((ext_vector_type(4))) float f32x4;
typedef __attribute__((ext_vector_type(8))) short s16x8;
typedef __attribute__((ext_vector_type(4))) short s16x4;

__device__ inline u16 f2bf(float f) {            // RNE float->bf16
  unsigned u = __float_as_uint(f);
  return (u16)((u + 0x7fffu + ((u >> 16) & 1u)) >> 16);
}
__device__ inline float bf2f(u16 h) { return __uint_as_float((unsigned)h << 16); }
__device__ inline float gate_fn(float a, float g) {
  float e2 = __expf(-2.f * fabsf(a));
  float th = (1.f - e2) * __builtin_amdgcn_rcpf(1.f + e2);
  float sg = __builtin_amdgcn_rcpf(1.f + __expf(-g));
  return copysignf(th, a) * sg;
}
__device__ inline void gload_lds16(const void* g, void* l) {
  __builtin_amdgcn_global_load_lds(
      (const __attribute__((address_space(1))) unsigned*)g,
      (__attribute__((address_space(3))) unsigned*)l, 16, 0, 0);
}

// ---------------- weight prep (merged) ----------------
__global__ void cvt_all(const float* __restrict__ conv_w, const float* __restrict__ skip_w,
                        const float* __restrict__ out_w, const float* __restrict__ first_w,
                        const float* __restrict__ last1_w, const float* __restrict__ last2_w,
                        u16* __restrict__ wcv, u16* __restrict__ wso, u16* __restrict__ wf,
                        u16* __restrict__ w1, u16* __restrict__ w2) {
  int i = blockIdx.x * 256 + threadIdx.x;
  if (i < 2359296) {  // conv: dst [l][k][o][c] <- src [l][o][c][k]
    int c = i & 127, o = (i >> 7) & 255, kk = (i >> 15) % 3, l = (i >> 15) / 3;
    wcv[i] = f2bf(conv_w[(((size_t)l * 256 + o) * 128 + c) * 3 + kk]);
    return;
  }
  i -= 2359296;
  if (i < 786432) {
    int c = i & 127, r = (i >> 7) & 255, l = i >> 15;
    float v = (r < 128) ? skip_w[((size_t)l * 128 + r) * 128 + c]
                        : out_w[((size_t)l * 128 + (r - 128)) * 128 + c];
    wso[i] = f2bf(v);
    return;
  }
  i -= 786432;
  if (i < 32768) { wf[i] = f2bf(first_w[i]); return; }
  i -= 32768;
  if (i < 16384) { w1[i] = f2bf(last1_w[i]); return; }
  i -= 16384;
  if (i < 32768) { w2[i] = f2bf(last2_w[i]); return; }
}
__global__ void sumsb_kernel(const float* __restrict__ sb, float* __restrict__ dst) {
  int c = threadIdx.x;  // 128
  float s = 0.f;
  for (int l = 0; l < NL; l++) s += sb[l * 128 + c];
  dst[c] = s;
}

// ---------------- first conv -> hi/lo bf16 shadow pair (no fp32 h) ----------------
// shHI: u16 at [(b*T+t)*128 + (c ^ ((t&7)<<3))]  (pre-swizzled, staged linearly)
// shLO: u16 at [(b*T+t)*128 + c]                 (plain; residual refinement plane)
__global__ __launch_bounds__(256, 2)
void first_kernel(const float* __restrict__ x, const u16* __restrict__ wf,
                  const float* __restrict__ fb, u16* __restrict__ shHI,
                  u16* __restrict__ shLO) {
  __shared__ u16 xT[64 * 256];
  const int tid = threadIdx.x, wv = tid >> 6, lane = tid & 63, lo = lane & 15, hi = lane >> 4;
  const int t0 = blockIdx.x * 64, b = blockIdx.y;
  #pragma unroll
  for (int it = 0; it < 16; it++) {
    int idx = tid + it * 256;
    int c = idx >> 4, t4 = (idx & 15) << 2;
    f32x4 v = *(const f32x4*)(x + ((size_t)b * CIN + c) * T + t0 + t4);
    #pragma unroll
    for (int i = 0; i < 4; i++) {
      int t = t4 + i;
      *(u16*)((char*)xT + t * 512 + ((c * 2) ^ ((t & 7) << 4))) = f2bf(v[i]);
    }
  }
  __syncthreads();
  f32x4 acc[2][4];
  #pragma unroll
  for (int m = 0; m < 2; m++)
    #pragma unroll
    for (int n = 0; n < 4; n++) acc[m][n] = (f32x4){0.f, 0.f, 0.f, 0.f};
  #pragma unroll
  for (int s = 0; s < 8; s++) {
    s16x8 af[2], bf[4];
    #pragma unroll
    for (int m = 0; m < 2; m++)
      af[m] = *(const s16x8*)(wf + (size_t)(wv * 32 + m * 16 + lo) * CIN + s * 32 + hi * 8);
    #pragma unroll
    for (int n = 0; n < 4; n++) {
      int t = n * 16 + lo;
      bf[n] = *(const s16x8*)((const char*)xT + t * 512 + ((s * 64 + hi * 16) ^ ((t & 7) << 4)));
    }
    #pragma unroll
    for (int m = 0; m < 2; m++)
      #pragma unroll
      for (int n = 0; n < 4; n++)
        acc[m][n] = __builtin_amdgcn_mfma_f32_16x16x32_bf16(af[m], bf[n], acc[m][n], 0, 0, 0);
  }
  #pragma unroll
  for (int m = 0; m < 2; m++) {
    int c0 = wv * 32 + m * 16 + hi * 4;
    f32x4 bv = *(const f32x4*)(fb + c0);
    #pragma unroll
    for (int n = 0; n < 4; n++) {
      int t = t0 + n * 16 + lo;
      f32x4 h = acc[m][n] + bv;
      s16x4 phi, plo;
      #pragma unroll
      for (int j = 0; j < 4; j++) {
        u16 hb = f2bf(h[j]);
        phi[j] = (short)hb;
        plo[j] = (short)f2bf(h[j] - bf2f(hb));
      }
      *(s16x4*)(shHI + ((size_t)b * T + t) * 128 + (c0 ^ ((lo & 7) << 3))) = phi;
      *(s16x4*)(shLO + ((size_t)b * T + t) * 128 + c0) = plo;
    }
  }
}

// ---------------- pair kernel: residual carried as hi/lo shadow pair ----------------
// Epilogue h0 = hi+lo read from GLOBAL (all cols, exact to 2^-17) — R13 dataflow
// with the fp32 plane replaced by two bf16 planes.
__global__ __launch_bounds__(512, 4)
void pair_kernel(const u16* __restrict__ shHI_in, const u16* __restrict__ shLO_in,
                 u16* __restrict__ shHI_out, u16* __restrict__ shLO_out,
                 float* __restrict__ skip,
                 const u16* __restrict__ wc1, const float* __restrict__ cb1,
                 const u16* __restrict__ ws1, const float* __restrict__ ob1,
                 const u16* __restrict__ wc2, const float* __restrict__ cb2,
                 const u16* __restrict__ ws2, const float* __restrict__ ob2,
                 int d1, int d2, int first) {
  extern __shared__ u16 lds[];
  u16* h_s = lds;              // 160 rows x 256B = 40KB (h0-hi, then h1 overlay [0,128))
  u16* zh  = lds + 160 * 128;  // 128 rows x 256B = 32KB
  const int tid = threadIdx.x, wv = tid >> 6, lane = tid & 63, lo = lane & 15, hi = lane >> 4;
  const int tj = blockIdx.x, b = blockIdx.y, t0 = tj * 64;
  const int R0 = 128 + 2 * d1;
  const int base_t = t0 - 64 - 2 * d1;   // t of LDS row 0

  // ---- stage: shHI (pre-swizzled) -> LDS, pure linear copy ----
  if (base_t >= 0) {
    const char* src = (const char*)(shHI_in + ((size_t)b * T + base_t) * 128);
    for (int rr = wv * 4; rr < R0; rr += 32)
      gload_lds16(src + rr * 256 + lane * 16, (char*)h_s + rr * 256);
  } else {
    for (int p = tid; p < R0 * 16; p += 512) {
      int r = p >> 4, q = p & 15;
      int t = base_t + r;
      s16x8 v = (s16x8){0, 0, 0, 0, 0, 0, 0, 0};
      if (t >= 0) v = *(const s16x8*)(shHI_in + ((size_t)b * T + t) * 128 + q * 8);
      *(s16x8*)((char*)h_s + r * 256 + q * 16) = v;
    }
  }
  __syncthreads();

  f32x4 A[2][8];
  const int oa = wv * 16, og = 128 + wv * 16;

  // ---- conv1 GEMM: N=128 cols ----
  #pragma unroll
  for (int m = 0; m < 2; m++)
    #pragma unroll
    for (int n = 0; n < 8; n++) A[m][n] = (f32x4){0.f, 0.f, 0.f, 0.f};
  #pragma unroll
  for (int k = 0; k < 3; k++) {
    const int st = ((lo + (k + 6) * d1) & 7) << 4;
    const int jb = k * d1;
    #pragma unroll
    for (int s = 0; s < 4; s++) {
      s16x8 af0 = *(const s16x8*)(wc1 + ((size_t)(k * 256 + oa + lo)) * 128 + s * 32 + hi * 8);
      s16x8 af1 = *(const s16x8*)(wc1 + ((size_t)(k * 256 + og + lo)) * 128 + s * 32 + hi * 8);
      const int cb_ = s * 64 + hi * 16;
      #pragma unroll
      for (int h2 = 0; h2 < 2; h2++) {
        s16x8 bf[4];
        #pragma unroll
        for (int nn = 0; nn < 4; nn++) {
          int j0 = (h2 * 4 + nn) * 16 + lo + jb;
          bf[nn] = *(const s16x8*)((const char*)h_s + j0 * 256 + (cb_ ^ st));
        }
        #pragma unroll
        for (int nn = 0; nn < 4; nn++) {
          A[0][h2 * 4 + nn] = __builtin_amdgcn_mfma_f32_16x16x32_bf16(af0, bf[nn], A[0][h2 * 4 + nn], 0, 0, 0);
          A[1][h2 * 4 + nn] = __builtin_amdgcn_mfma_f32_16x16x32_bf16(af1, bf[nn], A[1][h2 * 4 + nn], 0, 0, 0);
        }
      }
    }
  }
  // ---- gate1 -> zh (128 cols) ----
  {
    f32x4 ba = *(const f32x4*)(cb1 + oa + hi * 4);
    f32x4 bg = *(const f32x4*)(cb1 + og + hi * 4);
    #pragma unroll
    for (int n = 0; n < 8; n++) {
      int u = n * 16 + lo;
      s16x4 pk;
      #pragma unroll
      for (int j = 0; j < 4; j++)
        pk[j] = (short)f2bf(gate_fn(A[0][n][j] + ba[j], A[1][n][j] + bg[j]));
      *(s16x4*)((char*)zh + u * 256 + (((oa + hi * 4) * 2) ^ ((lo & 7) << 4))) = pk;
    }
  }
  __syncthreads();

  // ---- so1 GEMM ----
  const int ro = wv * 32;
  if (wv < 4) {
    #pragma unroll
    for (int m = 0; m < 2; m++)
      #pragma unroll
      for (int nn = 0; nn < 4; nn++) A[m][nn + 4] = (f32x4){0.f, 0.f, 0.f, 0.f};
    #pragma unroll
    for (int s = 0; s < 4; s++) {
      s16x8 af0 = *(const s16x8*)(ws1 + (size_t)(ro + lo) * 128 + s * 32 + hi * 8);
      s16x8 af1 = *(const s16x8*)(ws1 + (size_t)(ro + 16 + lo) * 128 + s * 32 + hi * 8);
      const int cb_ = s * 64 + hi * 16;
      s16x8 bf[4];
      #pragma unroll
      for (int nn = 0; nn < 4; nn++) {
        int u = (nn + 4) * 16 + lo;
        bf[nn] = *(const s16x8*)((const char*)zh + u * 256 + (cb_ ^ ((lo & 7) << 4)));
      }
      #pragma unroll
      for (int nn = 0; nn < 4; nn++) {
        A[0][nn + 4] = __builtin_amdgcn_mfma_f32_16x16x32_bf16(af0, bf[nn], A[0][nn + 4], 0, 0, 0);
        A[1][nn + 4] = __builtin_amdgcn_mfma_f32_16x16x32_bf16(af1, bf[nn], A[1][nn + 4], 0, 0, 0);
      }
    }
  } else {
    #pragma unroll
    for (int m = 0; m < 2; m++)
      #pragma unroll
      for (int n = 0; n < 8; n++) A[m][n] = (f32x4){0.f, 0.f, 0.f, 0.f};
    #pragma unroll
    for (int s = 0; s < 4; s++) {
      s16x8 af0 = *(const s16x8*)(ws1 + (size_t)(ro + lo) * 128 + s * 32 + hi * 8);
      s16x8 af1 = *(const s16x8*)(ws1 + (size_t)(ro + 16 + lo) * 128 + s * 32 + hi * 8);
      const int cb_ = s * 64 + hi * 16;
      #pragma unroll
      for (int h2 = 0; h2 < 2; h2++) {
        s16x8 bf[4];
        #pragma unroll
        for (int nn = 0; nn < 4; nn++) {
          int u = (h2 * 4 + nn) * 16 + lo;
          bf[nn] = *(const s16x8*)((const char*)zh + u * 256 + (cb_ ^ ((lo & 7) << 4)));
        }
        #pragma unroll
        for (int nn = 0; nn < 4; nn++) {
          A[0][h2 * 4 + nn] = __builtin_amdgcn_mfma_f32_16x16x32_bf16(af0, bf[nn], A[0][h2 * 4 + nn], 0, 0, 0);
          A[1][h2 * 4 + nn] = __builtin_amdgcn_mfma_f32_16x16x32_bf16(af1, bf[nn], A[1][h2 * 4 + nn], 0, 0, 0);
        }
      }
    }
    // epilogue-1: h1 = (so1 + ob1 + h0)*SH; h0 = hi+lo from GLOBAL shadow, all cols
    #pragma unroll
    for (int m = 0; m < 2; m++) {
      int c0 = (wv - 4) * 32 + m * 16 + hi * 4;
      f32x4 ob4 = *(const f32x4*)(ob1 + c0);
      #pragma unroll
      for (int n = 0; n < 8; n++) {
        int u = n * 16 + lo;
        int t_out = t0 - 64 + u;
        f32x4 h0 = (f32x4){0.f, 0.f, 0.f, 0.f};
        if (t_out >= 0) {
          s16x4 vhi = *(const s16x4*)(shHI_in + ((size_t)b * T + t_out) * 128 + (c0 ^ ((lo & 7) << 3)));
          s16x4 vlo = *(const s16x4*)(shLO_in + ((size_t)b * T + t_out) * 128 + c0);
          #pragma unroll
          for (int j = 0; j < 4; j++) h0[j] = bf2f((u16)vhi[j]) + bf2f((u16)vlo[j]);
        }
        f32x4 h1 = (A[m][n] + ob4 + h0) * SH;
        if (t_out < 0) h1 = (f32x4){0.f, 0.f, 0.f, 0.f};
        A[m][n] = h1;
        s16x4 pk;
        #pragma unroll
        for (int j = 0; j < 4; j++) pk[j] = (short)f2bf(h1[j]);
        *(s16x4*)((char*)h_s + u * 256 + ((c0 * 2) ^ ((lo & 7) << 4))) = pk;
      }
    }
  }
  __syncthreads();

  // ---- conv2 GEMM: N=64 own cols ----
  #pragma unroll
  for (int m = 0; m < 2; m++)
    #pragma unroll
    for (int n = 0; n < 4; n++) A[m][n] = (f32x4){0.f, 0.f, 0.f, 0.f};
  #pragma unroll
  for (int k = 0; k < 3; k++) {
    const int st = ((lo + (k + 6) * d2) & 7) << 4;
    const int jb2 = 64 - 2 * d2 + k * d2;
    #pragma unroll
    for (int s = 0; s < 4; s++) {
      s16x8 af0 = *(const s16x8*)(wc2 + ((size_t)(k * 256 + oa + lo)) * 128 + s * 32 + hi * 8);
      s16x8 af1 = *(const s16x8*)(wc2 + ((size_t)(k * 256 + og + lo)) * 128 + s * 32 + hi * 8);
      const int cb_ = s * 64 + hi * 16;
      s16x8 bf[4];
      #pragma unroll
      for (int nn = 0; nn < 4; nn++) {
        int j1 = nn * 16 + lo + jb2;
        bf[nn] = *(const s16x8*)((const char*)h_s + j1 * 256 + (cb_ ^ st));
      }
      #pragma unroll
      for (int nn = 0; nn < 4; nn++) {
        A[0][nn] = __builtin_amdgcn_mfma_f32_16x16x32_bf16(af0, bf[nn], A[0][nn], 0, 0, 0);
        A[1][nn] = __builtin_amdgcn_mfma_f32_16x16x32_bf16(af1, bf[nn], A[1][nn], 0, 0, 0);
      }
    }
  }
  // ---- gate2 -> zh rows [0,64) ----
  {
    f32x4 ba = *(const f32x4*)(cb2 + oa + hi * 4);
    f32x4 bg = *(const f32x4*)(cb2 + og + hi * 4);
    #pragma unroll
    for (int n = 0; n < 4; n++) {
      int u = n * 16 + lo;
      s16x4 pk;
      #pragma unroll
      for (int j = 0; j < 4; j++)
        pk[j] = (short)f2bf(gate_fn(A[0][n][j] + ba[j], A[1][n][j] + bg[j]));
      *(s16x4*)((char*)zh + u * 256 + (((oa + hi * 4) * 2) ^ ((lo & 7) << 4))) = pk;
    }
  }
  __syncthreads();

  // ---- so2 GEMM: N=64 ----
  if (wv < 4) {
    #pragma unroll
    for (int s = 0; s < 4; s++) {
      s16x8 af0 = *(const s16x8*)(ws2 + (size_t)(ro + lo) * 128 + s * 32 + hi * 8);
      s16x8 af1 = *(const s16x8*)(ws2 + (size_t)(ro + 16 + lo) * 128 + s * 32 + hi * 8);
      const int cb_ = s * 64 + hi * 16;
      s16x8 bf[4];
      #pragma unroll
      for (int nn = 0; nn < 4; nn++) {
        int u = nn * 16 + lo;
        bf[nn] = *(const s16x8*)((const char*)zh + u * 256 + (cb_ ^ ((lo & 7) << 4)));
      }
      #pragma unroll
      for (int nn = 0; nn < 4; nn++) {
        A[0][nn + 4] = __builtin_amdgcn_mfma_f32_16x16x32_bf16(af0, bf[nn], A[0][nn + 4], 0, 0, 0);
        A[1][nn + 4] = __builtin_amdgcn_mfma_f32_16x16x32_bf16(af1, bf[nn], A[1][nn + 4], 0, 0, 0);
      }
    }
    #pragma unroll
    for (int m = 0; m < 2; m++) {
      int c0 = ro + m * 16 + hi * 4;
      #pragma unroll
      for (int n = 0; n < 4; n++) {
        int t = t0 + n * 16 + lo;
        size_t off = ((size_t)b * T + t) * 128 + c0;
        f32x4 r = A[m][n + 4];
        if (!first) r += *(const f32x4*)(skip + off);
        *(f32x4*)(skip + off) = r;
      }
    }
  } else {
    #pragma unroll
    for (int m = 0; m < 2; m++)
      #pragma unroll
      for (int n = 0; n < 4; n++) A[m][n] = (f32x4){0.f, 0.f, 0.f, 0.f};
    #pragma unroll
    for (int s = 0; s < 4; s++) {
      s16x8 af0 = *(const s16x8*)(ws2 + (size_t)(ro + lo) * 128 + s * 32 + hi * 8);
      s16x8 af1 = *(const s16x8*)(ws2 + (size_t)(ro + 16 + lo) * 128 + s * 32 + hi * 8);
      const int cb_ = s * 64 + hi * 16;
      s16x8 bf[4];
      #pragma unroll
      for (int nn = 0; nn < 4; nn++) {
        int u = nn * 16 + lo;
        bf[nn] = *(const s16x8*)((const char*)zh + u * 256 + (cb_ ^ ((lo & 7) << 4)));
      }
      #pragma unroll
      for (int nn = 0; nn < 4; nn++) {
        A[0][nn] = __builtin_amdgcn_mfma_f32_16x16x32_bf16(af0, bf[nn], A[0][nn], 0, 0, 0);
        A[1][nn] = __builtin_amdgcn_mfma_f32_16x16x32_bf16(af1, bf[nn], A[1][nn], 0, 0, 0);
      }
    }
    #pragma unroll
    for (int m = 0; m < 2; m++) {
      int c0 = (wv - 4) * 32 + m * 16 + hi * 4;
      f32x4 ob4 = *(const f32x4*)(ob2 + c0);
      #pragma unroll
      for (int n = 0; n < 4; n++) {
        int t = t0 + n * 16 + lo;
        f32x4 h2v = (A[m][n] + ob4 + A[m][n + 4]) * SH;
        s16x4 phi, plo;
        #pragma unroll
        for (int j = 0; j < 4; j++) {
          u16 hb = f2bf(h2v[j]);
          phi[j] = (short)hb;
          plo[j] = (short)f2bf(h2v[j] - bf2f(hb));
        }
        *(s16x4*)(shHI_out + ((size_t)b * T + t) * 128 + (c0 ^ ((lo & 7) << 3))) = phi;
        *(s16x4*)(shLO_out + ((size_t)b * T + t) * 128 + c0) = plo;
      }
    }
  }
}

// ---------------- fused head ----------------
__global__ __launch_bounds__(256, 2)
void head_kernel(const float* __restrict__ skip, const float* __restrict__ sumsb,
                 const u16* __restrict__ w1, const float* __restrict__ b1v,
                 const u16* __restrict__ w2, const float* __restrict__ b2v,
                 float* __restrict__ out) {
  __shared__ u16 sT[64 * 128];
  __shared__ u16 s1T[64 * 128];
  const int tid = threadIdx.x, wv = tid >> 6, lane = tid & 63, lo = lane & 15, hi = lane >> 4;
  const int t0 = blockIdx.x * 64, b = blockIdx.y;

  #pragma unroll
  for (int it = 0; it < 8; it++) {
    int p = tid + it * 256;
    int t = p >> 5, cq = p & 31;
    f32x4 v = *(const f32x4*)(skip + ((size_t)b * T + t0 + t) * 128 + cq * 4);
    f32x4 sb4 = *(const f32x4*)(sumsb + cq * 4);
    s16x4 pk;
    #pragma unroll
    for (int j = 0; j < 4; j++) pk[j] = (short)f2bf(fmaxf((v[j] + sb4[j]) * SKIP_SCALE, 0.f));
    *(s16x4*)((char*)sT + t * 256 + ((cq * 8) ^ ((t & 7) << 4))) = pk;
  }
  __syncthreads();
  {
    f32x4 acc[2][4];
    #pragma unroll
    for (int m = 0; m < 2; m++)
      #pragma unroll
      for (int n = 0; n < 4; n++) acc[m][n] = (f32x4){0.f, 0.f, 0.f, 0.f};
    #pragma unroll
    for (int s = 0; s < 4; s++) {
      s16x8 af0 = *(const s16x8*)(w1 + (size_t)(wv * 32 + lo) * 128 + s * 32 + hi * 8);
      s16x8 af1 = *(const s16x8*)(w1 + (size_t)(wv * 32 + 16 + lo) * 128 + s * 32 + hi * 8);
      #pragma unroll
      for (int n = 0; n < 4; n++) {
        int t = n * 16 + lo;
        s16x8 bf = *(const s16x8*)((const char*)sT + t * 256 + ((s * 64 + hi * 16) ^ ((t & 7) << 4)));
        acc[0][n] = __builtin_amdgcn_mfma_f32_16x16x32_bf16(af0, bf, acc[0][n], 0, 0, 0);
        acc[1][n] = __builtin_amdgcn_mfma_f32_16x16x32_bf16(af1, bf, acc[1][n], 0, 0, 0);
      }
    }
    #pragma unroll
    for (int m = 0; m < 2; m++) {
      int c0 = wv * 32 + m * 16 + hi * 4;
      f32x4 bv = *(const f32x4*)(b1v + c0);
      #pragma unroll
      for (int n = 0; n < 4; n++) {
        int t = n * 16 + lo;
        s16x4 pk;
        #pragma unroll
        for (int j = 0; j < 4; j++) pk[j] = (short)f2bf(fmaxf(acc[m][n][j] + bv[j], 0.f));
        *(s16x4*)((char*)s1T + t * 256 + ((c0 * 2) ^ ((t & 7) << 4))) = pk;
      }
    }
  }
  __syncthreads();
  {
    f32x4 acc[4][4];
    #pragma unroll
    for (int m = 0; m < 4; m++)
      #pragma unroll
      for (int n = 0; n < 4; n++) acc[m][n] = (f32x4){0.f, 0.f, 0.f, 0.f};
    #pragma unroll
    for (int s = 0; s < 4; s++) {
      s16x8 af[4];
      #pragma unroll
      for (int m = 0; m < 4; m++)
        af[m] = *(const s16x8*)(w2 + (size_t)(wv * 64 + m * 16 + lo) * 128 + s * 32 + hi * 8);
      #pragma unroll
      for (int n = 0; n < 4; n++) {
        int t = n * 16 + lo;
        s16x8 bf = *(const s16x8*)((const char*)s1T + t * 256 + ((s * 64 + hi * 16) ^ ((t & 7) << 4)));
        #pragma unroll
        for (int m = 0; m < 4; m++)
          acc[m][n] = __builtin_amdgcn_mfma_f32_16x16x32_bf16(af[m], bf, acc[m][n], 0, 0, 0);
      }
    }
    #pragma unroll
    for (int m = 0; m < 4; m++) {
      int c0 = wv * 64 + m * 16 + hi * 4;
      f32x4 bv = *(const f32x4*)(b2v + c0);
      #pragma unroll
      for (int n = 0; n < 4; n++) {
        int t = t0 + n * 16 + lo;
        f32x4 r = acc[m][n] + bv;
        #pragma unroll
        for (int j = 0; j < 4; j++) out[((size_t)b * CIN + c0 + j) * T + t] = r[j];
      }
    }
  }
}

// ---------------------------------------------------------------------------
extern "C" void kernel_launch(void* const* d_in, const int* in_sizes, int n_in,
                              void* d_out, int out_size, void* d_ws, size_t ws_size,
                              hipStream_t stream) {
  const float* x       = (const float*)d_in[0];
  const float* first_w = (const float*)d_in[1];
  const float* first_b = (const float*)d_in[2];
  const float* conv_w  = (const float*)d_in[3];
  const float* conv_b  = (const float*)d_in[4];
  const float* out_w   = (const float*)d_in[5];
  const float* out_b   = (const float*)d_in[6];
  const float* skip_w  = (const float*)d_in[7];
  const float* skip_b  = (const float*)d_in[8];
  const float* last1_w = (const float*)d_in[9];
  const float* last1_b = (const float*)d_in[10];
  const float* last2_w = (const float*)d_in[11];
  const float* last2_b = (const float*)d_in[12];
  float* outp = (float*)d_out;

  const size_t NBT = (size_t)B * T * 128;        // 4,194,304 elements
  u16* wcv = (u16*)d_ws;                         // 2,359,296 u16
  u16* wso = wcv + (size_t)NL * 3 * 256 * 128;   // 786,432
  u16* wfB = wso + (size_t)NL * 256 * 128;       // 32,768
  u16* w1B = wfB + 128 * 256;                    // 16,384
  u16* w2B = w1B + 128 * 128;                    // 32,768
  float* sumsb = (float*)(w2B + 256 * 128);      // 128 f32
  float* skipF = sumsb + 128;                    // 16MB fp32 skip accumulator (ws)
  // 4 bf16 shadow buffers in d_out: 4*NBT*2B = out_size*4 bytes exactly.
  u16* shHI_A = (u16*)d_out;
  u16* shLO_A = shHI_A + NBT;
  u16* shHI_B = shLO_A + NBT;
  u16* shLO_B = shHI_B + NBT;

  cvt_all<<<12608, 256, 0, stream>>>(conv_w, skip_w, out_w, first_w, last1_w, last2_w,
                                     wcv, wso, wfB, w1B, w2B);
  sumsb_kernel<<<1, 128, 0, stream>>>(skip_b, sumsb);

  dim3 g64(T / 64, B);
  first_kernel<<<g64, 256, 0, stream>>>(x, wfB, first_b, shHI_A, shLO_A);

  for (int p = 0; p < NL / 2; p++) {
    int l1 = 2 * p, l2 = 2 * p + 1;
    int d1 = 1 << (l1 % 6), d2 = 1 << (l2 % 6);
    const u16* hiIn = (p & 1) ? shHI_B : shHI_A;
    const u16* loIn = (p & 1) ? shLO_B : shLO_A;
    u16* hiOut = (p & 1) ? shHI_A : shHI_B;
    u16* loOut = (p & 1) ? shLO_A : shLO_B;
    pair_kernel<<<g64, 512, 73728, stream>>>(
        hiIn, loIn, hiOut, loOut, skipF,
        wcv + (size_t)l1 * 3 * 256 * 128, conv_b + (size_t)l1 * 256,
        wso + (size_t)l1 * 256 * 128, out_b + (size_t)l1 * 128,
        wcv + (size_t)l2 * 3 * 256 * 128, conv_b + (size_t)l2 * 256,
        wso + (size_t)l2 * 256 * 128, out_b + (size_t)l2 * 128,
        d1, d2, p == 0 ? 1 : 0);
  }
  head_kernel<<<g64, 256, 0, stream>>>(skipF, sumsb, w1B, last1_b, w2B, last2_b, outp);
}